// Round 3
// baseline (771.543 us; speedup 1.0000x reference)
//
#include <hip/hip_runtime.h>

#define EPT 32   // edges per thread; N_EDGES (33,554,432) divisible by 32
#define BLK 256

typedef int  iv4 __attribute__((ext_vector_type(4)));

__global__ __launch_bounds__(BLK) void seg_gather_sum_kernel(
    const float* __restrict__ x,
    const int*   __restrict__ ptrs,
    const int*   __restrict__ csr,
    float*       __restrict__ out,
    int n_edges)
{
    long long tid = (long long)blockIdx.x * blockDim.x + threadIdx.x;
    long long e0  = tid * EPT;
    if (e0 >= n_edges) return;

    if (e0 + EPT <= n_edges) {
        // ---- streaming index loads: nontemporal (no reuse; keep L2 for x) ----
        const iv4* p4 = reinterpret_cast<const iv4*>(ptrs + e0);
        int ps[EPT];
        #pragma unroll
        for (int q = 0; q < EPT / 4; ++q) {
            iv4 p = __builtin_nontemporal_load(p4 + q);
            ps[q * 4 + 0] = p.x; ps[q * 4 + 1] = p.y;
            ps[q * 4 + 2] = p.z; ps[q * 4 + 3] = p.w;
        }

        // ---- issue all 32 gathers up front: 2x in-flight misses vs EPT=16 ----
        float v[EPT];
        #pragma unroll
        for (int i = 0; i < EPT; ++i) v[i] = x[ps[i]];

        // ---- csr loads overlap gather latency ----
        const iv4* c4 = reinterpret_cast<const iv4*>(csr + e0);
        int cs[EPT];
        #pragma unroll
        for (int q = 0; q < EPT / 4; ++q) {
            iv4 c = __builtin_nontemporal_load(c4 + q);
            cs[q * 4 + 0] = c.x; cs[q * 4 + 1] = c.y;
            cs[q * 4 + 2] = c.z; cs[q * 4 + 3] = c.w;
        }

        // ---- sorted-segment flush: interior runs exclusive -> plain nt store;
        //      chunk-boundary runs may be shared with neighbor threads -> atomic.
        int   cur   = cs[0];
        float sum   = 0.f;
        bool  first = true;
        #pragma unroll
        for (int i = 0; i < EPT; ++i) {
            int seg = cs[i];
            if (seg != cur) {
                if (first) { atomicAdd(out + cur, sum); first = false; }
                else       { __builtin_nontemporal_store(sum, out + cur); }
                cur = seg;
                sum = 0.f;
            }
            sum += v[i];
        }
        atomicAdd(out + cur, sum);
    } else {
        // scalar tail (unused at the fixed problem size)
        int   cur   = csr[e0];
        float sum   = 0.f;
        bool  first = true;
        for (long long e = e0; e < n_edges; ++e) {
            int seg = csr[e];
            if (seg != cur) {
                if (first) { atomicAdd(out + cur, sum); first = false; }
                else       { out[cur] = sum; }
                cur = seg;
                sum = 0.f;
            }
            sum += x[ptrs[e]];
        }
        atomicAdd(out + cur, sum);
    }
}

extern "C" void kernel_launch(void* const* d_in, const int* in_sizes, int n_in,
                              void* d_out, int out_size, void* d_ws, size_t ws_size,
                              hipStream_t stream) {
    const float* x    = (const float*)d_in[0];
    const int*   ptrs = (const int*)d_in[1];
    const int*   csr  = (const int*)d_in[2];
    float*       out  = (float*)d_out;

    const int n_edges = in_sizes[2];

    // Zero base for atomics + empty segments (d_out is poisoned by harness).
    (void)hipMemsetAsync(out, 0, (size_t)out_size * sizeof(float), stream);

    long long n_threads = ((long long)n_edges + EPT - 1) / EPT;
    long long blocks = (n_threads + BLK - 1) / BLK;
    seg_gather_sum_kernel<<<(int)blocks, BLK, 0, stream>>>(
        x, ptrs, csr, out, n_edges);
}